// Round 10
// baseline (109.782 us; speedup 1.0000x reference)
//
#include <hip/hip_runtime.h>
#include <stdint.h>

#define NFRAMES 2
#define NT 4           // NTYPES
#define BLK 256        // pair-kernel block size (4 waves)
#define NJ 64          // j-chunks: nloc/NJ = 64 atoms per tile
#define JT 64          // j-tile size (= nloc/NJ)
#define IPT 2          // atoms per thread in pair kernel
#define FBLK 64        // finalize block size (1 wave)
#define REP 10         // DIAGNOSTIC: hot-loop repeat factor (rep 0 is real)

// ---------------------------------------------------------------------------
// one pair interaction; bit-exact r2 vs numpy ((dx^2+dy^2)+dz^2, no contract)
// ---------------------------------------------------------------------------
template <bool SELFCHK>
__device__ __forceinline__ void do_pair(float cx, float cy, float cz, unsigned sval,
                                        int j, int i,
                                        float xi, float yi, float zi,
                                        float& mm, unsigned& cc) {
#pragma clang fp contract(off)
    float dx = cx - xi;
    float dy = cy - yi;
    float dz = cz - zi;
    float xx = dx * dx;
    float yy = dy * dy;
    float zz = dz * dz;
    float r2 = (xx + yy) + zz;
    bool self = SELFCHK && (j == i);
    mm = fminf(mm, self ? __builtin_inff() : r2);
    bool near = (r2 < 36.0f) && !self;
    cc += near ? sval : 0u;
}

// ---------------------------------------------------------------------------
// inner loop over the LDS j-tile: wave-uniform ds_read_b128 = HW broadcast
// ---------------------------------------------------------------------------
template <bool SELFCHK>
__device__ __forceinline__ void tile_loop(const float4* __restrict__ sj, int jbase,
                                          const int (&ii)[IPT],
                                          const float (&xi)[IPT],
                                          const float (&yi)[IPT],
                                          const float (&zi)[IPT],
                                          float (&mA)[IPT], float (&mB)[IPT],
                                          unsigned (&cA)[IPT], unsigned (&cB)[IPT]) {
#pragma unroll 8
    for (int l = 0; l < JT; l += 2) {
        float4 c0 = sj[l];
        float4 c1 = sj[l + 1];
        const unsigned s0 = __float_as_uint(c0.w);
        const unsigned s1 = __float_as_uint(c1.w);
        const int j0 = jbase + l;
#pragma unroll
        for (int k = 0; k < IPT; ++k)
            do_pair<SELFCHK>(c0.x, c0.y, c0.z, s0, j0, ii[k], xi[k], yi[k], zi[k], mA[k], cA[k]);
#pragma unroll
        for (int k = 0; k < IPT; ++k)
            do_pair<SELFCHK>(c1.x, c1.y, c1.z, s1, j0 + 1, ii[k], xi[k], yi[k], zi[k], mB[k], cB[k]);
    }
}

// ---------------------------------------------------------------------------
// pair kernel (DIAGNOSTIC: hot loop x REP, reps 1..REP-1 into live-kept
// shadow accumulators so only loop time scales; outputs unchanged)
// ---------------------------------------------------------------------------
__global__ __launch_bounds__(BLK) void ns_pair_kernel(const float* __restrict__ coord,
                                                      const int* __restrict__ atype,
                                                      uint2* __restrict__ part,
                                                      float* __restrict__ out,
                                                      int nloc) {
    const int f = blockIdx.z;
    const int q = nloc / IPT;                     // 2048
    const int ib = blockIdx.y * BLK;              // [0, q)
    const int jbase = blockIdx.x * JT;

    if (blockIdx.x == 0 && blockIdx.y == 0 && f == 0 && threadIdx.x < NFRAMES * NT)
        ((unsigned*)out)[(size_t)NFRAMES * nloc + threadIdx.x] = 0u;  // 0.0f bits

    const float* cf = coord + (size_t)f * nloc * 3;
    const int*   tf = atype + (size_t)f * nloc;

    __shared__ float4 sj[JT];
    if (threadIdx.x < JT) {
        const int jl = jbase + threadIdx.x;
        sj[threadIdx.x] = make_float4(cf[3 * jl], cf[3 * jl + 1], cf[3 * jl + 2],
                                      __uint_as_float(1u << (tf[jl] * 8)));
    }
    __syncthreads();

    int ii[IPT];
    float xi[IPT], yi[IPT], zi[IPT];
    float mA[IPT], mB[IPT], mS[IPT], mT[IPT];
    unsigned cA[IPT], cB[IPT], cS[IPT], cT[IPT];
    bool ov = false;
#pragma unroll
    for (int k = 0; k < IPT; ++k) {
        const int base = ib + k * q;
        ii[k] = base + threadIdx.x;
        xi[k] = cf[3 * ii[k]];
        yi[k] = cf[3 * ii[k] + 1];
        zi[k] = cf[3 * ii[k] + 2];
        mA[k] = mB[k] = mS[k] = mT[k] = __builtin_inff();
        cA[k] = cB[k] = cS[k] = cT[k] = 0u;
        ov |= (jbase >= base) && (jbase < base + BLK);   // 64-tile inside 256-range
    }

    if (ov) {
        tile_loop<true >(sj, jbase, ii, xi, yi, zi, mA, mB, cA, cB);
#pragma unroll 1
        for (int rep = 1; rep < REP; ++rep)
            tile_loop<true >(sj, jbase, ii, xi, yi, zi, mS, mT, cS, cT);
    } else {
        tile_loop<false>(sj, jbase, ii, xi, yi, zi, mA, mB, cA, cB);
#pragma unroll 1
        for (int rep = 1; rep < REP; ++rep)
            tile_loop<false>(sj, jbase, ii, xi, yi, zi, mS, mT, cS, cT);
    }

    // keep shadow results live without memory traffic (rule #17)
#pragma unroll
    for (int k = 0; k < IPT; ++k)
        asm volatile("" :: "v"(mS[k]), "v"(mT[k]), "v"(cS[k]), "v"(cT[k]));

    const size_t pb = ((size_t)blockIdx.x * NFRAMES + f) * nloc;
#pragma unroll
    for (int k = 0; k < IPT; ++k)
        part[pb + ii[k]] = make_uint2(__float_as_uint(fminf(mA[k], mB[k])), cA[k] + cB[k]);
}

// ---------------------------------------------------------------------------
// finalize: one wave per 64 atoms; reduce NJ=64 partials per atom; write
// min_rr2; fold per-type count maxes into out tail via atomicMax on float bits
// ---------------------------------------------------------------------------
__global__ __launch_bounds__(FBLK) void ns_finalize_kernel(const uint2* __restrict__ part,
                                                           float* __restrict__ out,
                                                           int nloc) {
    const int nbpf = nloc / FBLK;                 // 64 blocks per frame
    const int f = blockIdx.x / nbpf;
    const int i = (blockIdx.x % nbpf) * FBLK + threadIdx.x;

    float ma = __builtin_inff(), mb = __builtin_inff();
    unsigned cacc = 0u, cbacc = 0u;
#pragma unroll 16
    for (int jb = 0; jb < NJ; jb += 2) {
        uint2 va = part[((size_t)jb * NFRAMES + f) * nloc + i];
        uint2 vb = part[((size_t)(jb + 1) * NFRAMES + f) * nloc + i];
        ma = fminf(ma, __uint_as_float(va.x));
        mb = fminf(mb, __uint_as_float(vb.x));
        cacc += va.y;
        cbacc += vb.y;
    }
    out[(size_t)f * nloc + i] = fminf(ma, mb);
    const unsigned c = cacc + cbacc;

    int m0 = (int)(c & 255u);
    int m1 = (int)((c >> 8) & 255u);
    int m2 = (int)((c >> 16) & 255u);
    int m3 = (int)(c >> 24);
    for (int off = 32; off > 0; off >>= 1) {
        m0 = max(m0, __shfl_xor(m0, off, 64));
        m1 = max(m1, __shfl_xor(m1, off, 64));
        m2 = max(m2, __shfl_xor(m2, off, 64));
        m3 = max(m3, __shfl_xor(m3, off, 64));
    }
    if (threadIdx.x < NT) {
        const int t = threadIdx.x;
        const int mv = (t == 0) ? m0 : (t == 1) ? m1 : (t == 2) ? m2 : m3;
        atomicMax((unsigned*)out + (size_t)NFRAMES * nloc + f * NT + t,
                  __float_as_uint((float)mv));
    }
}

extern "C" void kernel_launch(void* const* d_in, const int* in_sizes, int n_in,
                              void* d_out, int out_size, void* d_ws, size_t ws_size,
                              hipStream_t stream) {
    const float* coord = (const float*)d_in[0];
    const int*   atype = (const int*)d_in[1];
    const int nloc = in_sizes[1] / NFRAMES;

    float* out  = (float*)d_out;
    uint2* part = (uint2*)d_ws;                   // NJ * NFRAMES * nloc uint2

    dim3 grid(NJ, nloc / (BLK * IPT), NFRAMES);
    ns_pair_kernel<<<grid, dim3(BLK), 0, stream>>>(coord, atype, part, out, nloc);

    const int nbpf = nloc / FBLK;
    ns_finalize_kernel<<<NFRAMES * nbpf, FBLK, 0, stream>>>(part, out, nloc);
}

// Round 11
// 28.033 us; speedup vs baseline: 3.9162x; 3.9162x over previous
//
#include <hip/hip_runtime.h>
#include <stdint.h>

#define NFRAMES 2
#define NT 4           // NTYPES
#define BLK 256        // pair-kernel block size (4 waves)
#define NJ 128         // j-chunks: nloc/NJ = 32 atoms per tile
#define JT 32          // j-tile size (= nloc/NJ)
#define IPT 2          // atoms per thread in pair kernel
#define FBLK 64        // finalize block size (1 wave)

typedef float f32x2 __attribute__((ext_vector_type(2)));

// ---------------------------------------------------------------------------
// packed inner loop over the SoA LDS j-tile: 2 j-atoms per step via v_pk_*
// f32 ops (full-rate packed on CDNA). FMA allowed (threshold 0.56 >> 1ulp).
// ---------------------------------------------------------------------------
template <bool SELFCHK>
__device__ __forceinline__ void tile_loop(const f32x2* __restrict__ px,
                                          const f32x2* __restrict__ py,
                                          const f32x2* __restrict__ pz,
                                          const uint2* __restrict__ ps,
                                          int jbase,
                                          const int (&ii)[IPT],
                                          const f32x2 (&Xi)[IPT],
                                          const f32x2 (&Yi)[IPT],
                                          const f32x2 (&Zi)[IPT],
                                          float (&mm)[IPT],
                                          unsigned (&cA)[IPT], unsigned (&cB)[IPT]) {
#pragma unroll
    for (int h = 0; h < JT / 2; ++h) {
        const f32x2 jx = px[h], jy = py[h], jz = pz[h];   // uniform ds_read_b64
        const uint2 s2 = ps[h];
        const int j0 = jbase + 2 * h;
#pragma unroll
        for (int k = 0; k < IPT; ++k) {
            f32x2 dx = jx - Xi[k];                        // v_pk_add (neg)
            f32x2 dy = jy - Yi[k];
            f32x2 dz = jz - Zi[k];
            f32x2 zz = dz * dz;                           // v_pk_mul
            f32x2 t  = __builtin_elementwise_fma(dy, dy, zz);   // v_pk_fma
            f32x2 r2 = __builtin_elementwise_fma(dx, dx, t);    // v_pk_fma
            if (SELFCHK) {
                r2.x = (j0     == ii[k]) ? __builtin_inff() : r2.x;
                r2.y = (j0 + 1 == ii[k]) ? __builtin_inff() : r2.y;
            }
            mm[k] = fminf(mm[k], fminf(r2.x, r2.y));      // v_min3
            cA[k] += (r2.x < 36.0f) ? s2.x : 0u;
            cB[k] += (r2.y < 36.0f) ? s2.y : 0u;
        }
    }
}

// ---------------------------------------------------------------------------
// pair kernel: block stages a 32-atom j-tile into SoA LDS, each thread owns
// IPT=2 atoms. Writes partial {min_bits, packed_cnt}; no atomics. Block
// (0,0,0) zeroes the 8 output tail slots for finalize's atomicMax.
// ---------------------------------------------------------------------------
__global__ __launch_bounds__(BLK) void ns_pair_kernel(const float* __restrict__ coord,
                                                      const int* __restrict__ atype,
                                                      uint2* __restrict__ part,
                                                      float* __restrict__ out,
                                                      int nloc) {
    const int f = blockIdx.z;
    const int q = nloc / IPT;                     // 2048
    const int ib = blockIdx.y * BLK;              // [0, q)
    const int jbase = blockIdx.x * JT;

    if (blockIdx.x == 0 && blockIdx.y == 0 && f == 0 && threadIdx.x < NFRAMES * NT)
        ((unsigned*)out)[(size_t)NFRAMES * nloc + threadIdx.x] = 0u;  // 0.0f bits

    const float* cf = coord + (size_t)f * nloc * 3;
    const int*   tf = atype + (size_t)f * nloc;

    __shared__ float    sx[JT], sy[JT], sz[JT];
    __shared__ unsigned st[JT];
    if (threadIdx.x < JT) {
        const int jl = jbase + threadIdx.x;
        sx[threadIdx.x] = cf[3 * jl];
        sy[threadIdx.x] = cf[3 * jl + 1];
        sz[threadIdx.x] = cf[3 * jl + 2];
        st[threadIdx.x] = 1u << (tf[jl] * 8);
    }
    __syncthreads();

    int ii[IPT];
    f32x2 Xi[IPT], Yi[IPT], Zi[IPT];
    float mm[IPT];
    unsigned cA[IPT], cB[IPT];
    bool ov = false;
#pragma unroll
    for (int k = 0; k < IPT; ++k) {
        const int base = ib + k * q;
        ii[k] = base + threadIdx.x;
        const float x = cf[3 * ii[k]], y = cf[3 * ii[k] + 1], z = cf[3 * ii[k] + 2];
        Xi[k] = (f32x2){x, x};
        Yi[k] = (f32x2){y, y};
        Zi[k] = (f32x2){z, z};
        mm[k] = __builtin_inff();
        cA[k] = cB[k] = 0u;
        ov |= (jbase >= base) && (jbase < base + BLK);   // 32-tile inside 256-range
    }

    const f32x2* px = (const f32x2*)sx;
    const f32x2* py = (const f32x2*)sy;
    const f32x2* pz = (const f32x2*)sz;
    const uint2* ps = (const uint2*)st;

    if (ov)
        tile_loop<true >(px, py, pz, ps, jbase, ii, Xi, Yi, Zi, mm, cA, cB);
    else
        tile_loop<false>(px, py, pz, ps, jbase, ii, Xi, Yi, Zi, mm, cA, cB);

    const size_t pb = ((size_t)blockIdx.x * NFRAMES + f) * nloc;
#pragma unroll
    for (int k = 0; k < IPT; ++k)
        part[pb + ii[k]] = make_uint2(__float_as_uint(mm[k]), cA[k] + cB[k]);
}

// ---------------------------------------------------------------------------
// finalize: one wave per 64 atoms; reduce NJ=128 partials per atom; write
// min_rr2; fold per-type count maxes into out tail via atomicMax on float bits
// ---------------------------------------------------------------------------
__global__ __launch_bounds__(FBLK) void ns_finalize_kernel(const uint2* __restrict__ part,
                                                           float* __restrict__ out,
                                                           int nloc) {
    const int nbpf = nloc / FBLK;                 // 64 blocks per frame
    const int f = blockIdx.x / nbpf;
    const int i = (blockIdx.x % nbpf) * FBLK + threadIdx.x;

    float ma = __builtin_inff(), mb = __builtin_inff();
    unsigned cacc = 0u, cbacc = 0u;
#pragma unroll 16
    for (int jb = 0; jb < NJ; jb += 2) {
        uint2 va = part[((size_t)jb * NFRAMES + f) * nloc + i];
        uint2 vb = part[((size_t)(jb + 1) * NFRAMES + f) * nloc + i];
        ma = fminf(ma, __uint_as_float(va.x));
        mb = fminf(mb, __uint_as_float(vb.x));
        cacc += va.y;
        cbacc += vb.y;
    }
    out[(size_t)f * nloc + i] = fminf(ma, mb);
    const unsigned c = cacc + cbacc;

    int m0 = (int)(c & 255u);
    int m1 = (int)((c >> 8) & 255u);
    int m2 = (int)((c >> 16) & 255u);
    int m3 = (int)(c >> 24);
    for (int off = 32; off > 0; off >>= 1) {
        m0 = max(m0, __shfl_xor(m0, off, 64));
        m1 = max(m1, __shfl_xor(m1, off, 64));
        m2 = max(m2, __shfl_xor(m2, off, 64));
        m3 = max(m3, __shfl_xor(m3, off, 64));
    }
    if (threadIdx.x < NT) {
        const int t = threadIdx.x;
        const int mv = (t == 0) ? m0 : (t == 1) ? m1 : (t == 2) ? m2 : m3;
        atomicMax((unsigned*)out + (size_t)NFRAMES * nloc + f * NT + t,
                  __float_as_uint((float)mv));
    }
}

extern "C" void kernel_launch(void* const* d_in, const int* in_sizes, int n_in,
                              void* d_out, int out_size, void* d_ws, size_t ws_size,
                              hipStream_t stream) {
    const float* coord = (const float*)d_in[0];
    const int*   atype = (const int*)d_in[1];
    const int nloc = in_sizes[1] / NFRAMES;

    float* out  = (float*)d_out;
    uint2* part = (uint2*)d_ws;                   // NJ * NFRAMES * nloc uint2

    dim3 grid(NJ, nloc / (BLK * IPT), NFRAMES);
    ns_pair_kernel<<<grid, dim3(BLK), 0, stream>>>(coord, atype, part, out, nloc);

    const int nbpf = nloc / FBLK;
    ns_finalize_kernel<<<NFRAMES * nbpf, FBLK, 0, stream>>>(part, out, nloc);
}

// Round 12
// 24.026 us; speedup vs baseline: 4.5693x; 1.1668x over previous
//
#include <hip/hip_runtime.h>
#include <stdint.h>

#define NFRAMES 2
#define NT 4           // NTYPES
#define BLK 256        // pair-kernel block size (4 waves)
#define NJ 64          // j-chunks: nloc/NJ = 64 atoms per tile
#define JT 64          // j-tile size (= nloc/NJ)
#define IPT 2          // atoms per thread in pair kernel
#define FBLK 64        // finalize block size (1 wave)

typedef float f32x2 __attribute__((ext_vector_type(2)));

// ---------------------------------------------------------------------------
// 2 pairs via packed VOP3P f32 math (guaranteed by inline asm):
// r2 = (j - i)^2 summed; i-coords pre-negated so only v_pk_add is needed.
// ---------------------------------------------------------------------------
__device__ __forceinline__ f32x2 pk_r2(f32x2 jx, f32x2 jy, f32x2 jz,
                                       f32x2 nx, f32x2 ny, f32x2 nz) {
    f32x2 dx, dy, dz, t1, t2, r2;
    asm("v_pk_add_f32 %0, %1, %2" : "=v"(dx) : "v"(jx), "v"(nx));
    asm("v_pk_add_f32 %0, %1, %2" : "=v"(dy) : "v"(jy), "v"(ny));
    asm("v_pk_add_f32 %0, %1, %2" : "=v"(dz) : "v"(jz), "v"(nz));
    asm("v_pk_mul_f32 %0, %1, %1" : "=v"(t1) : "v"(dz));
    asm("v_pk_fma_f32 %0, %1, %1, %2" : "=v"(t2) : "v"(dy), "v"(t1));
    asm("v_pk_fma_f32 %0, %1, %1, %2" : "=v"(r2) : "v"(dx), "v"(t2));
    return r2;
}

// ---------------------------------------------------------------------------
// inner loop over the LDS j-tile (pair-AoS): per h-step, 2 uniform
// ds_read_b128 feed 2 j-atoms x IPT i-atoms = 4 pairs of packed math.
// Self-exclusion: inf-inject into lo/hi, which also kills the count (inf<36
// is false).
// ---------------------------------------------------------------------------
template <bool SELFCHK>
__device__ __forceinline__ void tile_loop(const float4* __restrict__ A,
                                          const float4* __restrict__ B,
                                          int jbase,
                                          const int (&ii)[IPT],
                                          const f32x2 (&nX)[IPT],
                                          const f32x2 (&nY)[IPT],
                                          const f32x2 (&nZ)[IPT],
                                          float (&mm)[IPT],
                                          unsigned (&cA)[IPT], unsigned (&cB)[IPT]) {
#pragma unroll 8
    for (int h = 0; h < JT / 2; ++h) {
        const float4 a = A[h];                    // {x0,x1,y0,y1}
        const float4 b = B[h];                    // {z0,z1,s0bits,s1bits}
        const f32x2 jx = {a.x, a.y};
        const f32x2 jy = {a.z, a.w};
        const f32x2 jz = {b.x, b.y};
        const unsigned s0 = __float_as_uint(b.z);
        const unsigned s1 = __float_as_uint(b.w);
        const int j0 = jbase + 2 * h;
#pragma unroll
        for (int k = 0; k < IPT; ++k) {
            f32x2 r2 = pk_r2(jx, jy, jz, nX[k], nY[k], nZ[k]);
            float lo = r2.x, hi = r2.y;
            if (SELFCHK) {
                lo = (j0     == ii[k]) ? __builtin_inff() : lo;
                hi = (j0 + 1 == ii[k]) ? __builtin_inff() : hi;
            }
            mm[k] = fminf(mm[k], fminf(lo, hi));  // v_min3
            cA[k] += (lo < 36.0f) ? s0 : 0u;
            cB[k] += (hi < 36.0f) ? s1 : 0u;
        }
    }
}

// ---------------------------------------------------------------------------
// pair kernel: block stages its 64-atom j-tile into pair-AoS LDS; each thread
// owns IPT=2 atoms with pre-negated coords. Writes partial {min_bits,
// packed_cnt}; no atomics. Block (0,0,0) zeroes the 8 output tail slots.
// ---------------------------------------------------------------------------
__global__ __launch_bounds__(BLK) void ns_pair_kernel(const float* __restrict__ coord,
                                                      const int* __restrict__ atype,
                                                      uint2* __restrict__ part,
                                                      float* __restrict__ out,
                                                      int nloc) {
    const int f = blockIdx.z;
    const int q = nloc / IPT;                     // 2048
    const int ib = blockIdx.y * BLK;              // [0, q)
    const int jbase = blockIdx.x * JT;

    if (blockIdx.x == 0 && blockIdx.y == 0 && f == 0 && threadIdx.x < NFRAMES * NT)
        ((unsigned*)out)[(size_t)NFRAMES * nloc + threadIdx.x] = 0u;  // 0.0f bits

    const float* cf = coord + (size_t)f * nloc * 3;
    const int*   tf = atype + (size_t)f * nloc;

    __shared__ float4 A[JT / 2], B[JT / 2];
    if (threadIdx.x < JT / 2) {
        const int j0 = jbase + 2 * threadIdx.x;
        A[threadIdx.x] = make_float4(cf[3 * j0], cf[3 * j0 + 3],
                                     cf[3 * j0 + 1], cf[3 * j0 + 4]);
        B[threadIdx.x] = make_float4(cf[3 * j0 + 2], cf[3 * j0 + 5],
                                     __uint_as_float(1u << (tf[j0] * 8)),
                                     __uint_as_float(1u << (tf[j0 + 1] * 8)));
    }
    __syncthreads();

    int ii[IPT];
    f32x2 nX[IPT], nY[IPT], nZ[IPT];
    float mm[IPT];
    unsigned cA[IPT], cB[IPT];
    bool ov = false;
#pragma unroll
    for (int k = 0; k < IPT; ++k) {
        const int base = ib + k * q;
        ii[k] = base + threadIdx.x;
        const float nx = -cf[3 * ii[k]];
        const float ny = -cf[3 * ii[k] + 1];
        const float nz = -cf[3 * ii[k] + 2];
        nX[k] = (f32x2){nx, nx};
        nY[k] = (f32x2){ny, ny};
        nZ[k] = (f32x2){nz, nz};
        mm[k] = __builtin_inff();
        cA[k] = cB[k] = 0u;
        ov |= (jbase >= base) && (jbase < base + BLK);   // 64-tile inside 256-range
    }

    if (ov)
        tile_loop<true >(A, B, jbase, ii, nX, nY, nZ, mm, cA, cB);
    else
        tile_loop<false>(A, B, jbase, ii, nX, nY, nZ, mm, cA, cB);

    const size_t pb = ((size_t)blockIdx.x * NFRAMES + f) * nloc;
#pragma unroll
    for (int k = 0; k < IPT; ++k)
        part[pb + ii[k]] = make_uint2(__float_as_uint(mm[k]), cA[k] + cB[k]);
}

// ---------------------------------------------------------------------------
// finalize: one wave per 64 atoms; reduce NJ=64 partials per atom; write
// min_rr2; fold per-type count maxes into out tail via atomicMax on float bits
// ---------------------------------------------------------------------------
__global__ __launch_bounds__(FBLK) void ns_finalize_kernel(const uint2* __restrict__ part,
                                                           float* __restrict__ out,
                                                           int nloc) {
    const int nbpf = nloc / FBLK;                 // 64 blocks per frame
    const int f = blockIdx.x / nbpf;
    const int i = (blockIdx.x % nbpf) * FBLK + threadIdx.x;

    float ma = __builtin_inff(), mb = __builtin_inff();
    unsigned cacc = 0u, cbacc = 0u;
#pragma unroll 16
    for (int jb = 0; jb < NJ; jb += 2) {
        uint2 va = part[((size_t)jb * NFRAMES + f) * nloc + i];
        uint2 vb = part[((size_t)(jb + 1) * NFRAMES + f) * nloc + i];
        ma = fminf(ma, __uint_as_float(va.x));
        mb = fminf(mb, __uint_as_float(vb.x));
        cacc += va.y;
        cbacc += vb.y;
    }
    out[(size_t)f * nloc + i] = fminf(ma, mb);
    const unsigned c = cacc + cbacc;

    int m0 = (int)(c & 255u);
    int m1 = (int)((c >> 8) & 255u);
    int m2 = (int)((c >> 16) & 255u);
    int m3 = (int)(c >> 24);
    for (int off = 32; off > 0; off >>= 1) {
        m0 = max(m0, __shfl_xor(m0, off, 64));
        m1 = max(m1, __shfl_xor(m1, off, 64));
        m2 = max(m2, __shfl_xor(m2, off, 64));
        m3 = max(m3, __shfl_xor(m3, off, 64));
    }
    if (threadIdx.x < NT) {
        const int t = threadIdx.x;
        const int mv = (t == 0) ? m0 : (t == 1) ? m1 : (t == 2) ? m2 : m3;
        atomicMax((unsigned*)out + (size_t)NFRAMES * nloc + f * NT + t,
                  __float_as_uint((float)mv));
    }
}

extern "C" void kernel_launch(void* const* d_in, const int* in_sizes, int n_in,
                              void* d_out, int out_size, void* d_ws, size_t ws_size,
                              hipStream_t stream) {
    const float* coord = (const float*)d_in[0];
    const int*   atype = (const int*)d_in[1];
    const int nloc = in_sizes[1] / NFRAMES;

    float* out  = (float*)d_out;
    uint2* part = (uint2*)d_ws;                   // NJ * NFRAMES * nloc uint2

    dim3 grid(NJ, nloc / (BLK * IPT), NFRAMES);
    ns_pair_kernel<<<grid, dim3(BLK), 0, stream>>>(coord, atype, part, out, nloc);

    const int nbpf = nloc / FBLK;
    ns_finalize_kernel<<<NFRAMES * nbpf, FBLK, 0, stream>>>(part, out, nloc);
}